// Round 4
// baseline (340.133 us; speedup 1.0000x reference)
//
#include <hip/hip_runtime.h>
#include <math.h>

#define IN_C   256
#define OUT_C  512
#define HW     3136
#define W_     56
#define D_     2304
#define TBL    16

// ws layout (4-byte units):
// [0,2304)      max_row (float)           (fallback path only)
// [2304,2816)   hashk (int)
// [2816]        qidx (int)
// [2817]        count_eff (int)
// [2818]        scale_mul (float)
// [2819,3331)   active (int)
// [3331,3843)   inact (int, fast path) / flags (fallback)
// byte 16384+   Wc: bf16 weights [512][2304] (fast path: ALL rows, no compaction)
// byte 2375680+ Xb: bf16 padded x [cg=8][n=16][yp=58][wp=58][c=32]
// byte 29933568+ P: chanmax partials [part=4][tap=9][c=256] float (fast path)

#define XB_OFF 2375680ULL
#define XB_ROW 1856            // ushorts per (cg,n,yp) row: 58*32
#define P_OFF  7483392         // float index of partials (byte 29933568)

typedef __attribute__((ext_vector_type(8))) __bf16 bf16x8;
typedef __attribute__((ext_vector_type(4))) float f32x4;

__device__ __forceinline__ ushort f2bf(float f) {
  uint b = __float_as_uint(f);
  b = b + 0x7FFFu + ((b >> 16) & 1u);
  return (ushort)(b >> 16);
}

// ================= FAST PATH =================

// ---------- Kernel S: fused setup ----------
// blocks [0,3712): xprep | [3712,4736): chanmax partials | [4736,5248): khash
// [5248,5760): wprep — bf16-convert ALL 512 kernel rows (no compaction needed;
// conv reads rows via active[] indirection).
__global__ __launch_bounds__(256) void k_setup(const float* __restrict__ x,
                                               const float* __restrict__ kern,
                                               const float* __restrict__ a,
                                               float* __restrict__ ws) {
  __shared__ __align__(16) float smem[64 * 57];  // 14592 B, aliased per path
  int bx = blockIdx.x, t = threadIdx.x;

  if (bx < 3712) {
    // ---- xprep: fp32 NCHW -> bf16 padded [cg][n][58][58][32], one 64-ch chunk ----
    int c0i = bx & 3;             // 64-channel chunk
    int n = (bx >> 2) & 15;
    int yp = bx >> 6;             // 0..57
    int c0 = c0i * 64, cgbase = c0i * 2;
    ushort* xb = (ushort*)((char*)ws + XB_OFF);
    const size_t CGS = (size_t)16 * 58 * XB_ROW;
    size_t rb0 = (size_t)(n * 58 + yp) * XB_ROW;
    uint4 z4 = make_uint4(0u, 0u, 0u, 0u);

    if (yp == 0 || yp == 57) {    // border rows: zeros for this block's 2 cgs
      for (int e = t; e < 464; e += 256) {
        int cg_l = e / 232, k = e - cg_l * 232;
        *(uint4*)&xb[rb0 + (size_t)(cgbase + cg_l) * CGS + (size_t)k * 8] = z4;
      }
      return;
    }
    if (t < 16) {                 // column borders wp = 0, 57
      int cg_l = t >> 3, r = t & 7;
      int wp = (r >> 2) ? 57 : 0, oct = r & 3;
      *(uint4*)&xb[rb0 + (size_t)(cgbase + cg_l) * CGS + wp * 32 + oct * 8] = z4;
    }
    int y = yp - 1;
    float* Lf = smem;             // [64][57]
    for (int e = t; e < 3584; e += 256) {
      int ci = e / 56, w = e - ci * 56;
      Lf[ci * 57 + w] = x[(size_t)(n * 256 + c0 + ci) * 3136 + y * 56 + w];
    }
    __syncthreads();
    for (int e = t; e < 448; e += 256) {
      int w = e >> 3, cg_l = (e >> 2) & 1, oct = e & 3;
      int cb = cg_l * 32 + oct * 8;
      uint pk[4];
#pragma unroll
      for (int k = 0; k < 4; k++) {
        uint lo = f2bf(Lf[(cb + 2 * k) * 57 + w]);
        uint hi = f2bf(Lf[(cb + 2 * k + 1) * 57 + w]);
        pk[k] = lo | (hi << 16);
      }
      *(uint4*)&xb[rb0 + (size_t)(cgbase + cg_l) * CGS + (w + 1) * 32 + oct * 8] =
          make_uint4(pk[0], pk[1], pk[2], pk[3]);
    }
  } else if (bx < 4736) {
    // ---- chanmax partial: 4 blocks/channel, 4 images each ----
    int idx = bx - 3712;
    int c = idx & 255, part = idx >> 8;
    float m[3][3];
#pragma unroll
    for (int i = 0; i < 3; i++)
#pragma unroll
      for (int j = 0; j < 3; j++) m[i][j] = -INFINITY;
    for (int e = t; e < 4 * HW; e += 256) {
      int nl = e / HW;
      int rem = e - nl * HW;
      int r = rem / W_;
      int s = rem - r * W_;
      float v = x[(size_t)((part * 4 + nl) * IN_C + c) * HW + rem];
      bool rc[3] = { r <= 54, true, r >= 1 };
      bool sc[3] = { s <= 54, true, s >= 1 };
#pragma unroll
      for (int i = 0; i < 3; i++)
#pragma unroll
        for (int j = 0; j < 3; j++)
          if (rc[i] && sc[j]) m[i][j] = fmaxf(m[i][j], v);
    }
#pragma unroll
    for (int i = 0; i < 3; i++)
#pragma unroll
      for (int j = 0; j < 3; j++)
        for (int o = 32; o; o >>= 1)
          m[i][j] = fmaxf(m[i][j], __shfl_down(m[i][j], o, 64));
    float* red = smem;            // [4][9]
    int lane = t & 63, wid = t >> 6;
    if (lane == 0) {
#pragma unroll
      for (int i = 0; i < 3; i++)
#pragma unroll
        for (int j = 0; j < 3; j++) red[wid * 9 + i * 3 + j] = m[i][j];
    }
    __syncthreads();
    if (t < 9) {
      float v = fmaxf(fmaxf(red[0 * 9 + t], red[1 * 9 + t]),
                      fmaxf(red[2 * 9 + t], red[3 * 9 + t]));
      ws[P_OFF + (size_t)part * 2304 + (size_t)t * IN_C + c] = v;  // no 0-cap here
    }
  } else if (bx < 5248) {
    // ---- khash: per-kernel-row hash ----
    int o = bx - 4736;
    const float* kr = kern + (size_t)o * D_;
    double sd = 0, sn = 0;
    for (int d = t; d < D_; d += 256) {
      double w = (double)kr[d];
      sd += (double)a[d] * w;
      sn += w * w;
    }
    double* sh = (double*)smem;
    double* sh2 = sh + 8;
    int lane = t & 63, wid = t >> 6;
    for (int off = 32; off; off >>= 1) {
      sd += __shfl_down(sd, off, 64);
      sn += __shfl_down(sn, off, 64);
    }
    if (lane == 0) { sh[wid] = sd; sh2[wid] = sn; }
    __syncthreads();
    if (t == 0) {
      double td = 0, tn = 0;
      for (int w = 0; w < 4; w++) { td += sh[w]; tn += sh2[w]; }
      double p1 = tn, p2 = p1 * p1, p4 = p2 * p2, p8 = p4 * p4, p16 = p8 * p8;
      td += (double)a[D_] * p1 + (double)a[D_ + 1] * p2 + (double)a[D_ + 2] * p4 +
            (double)a[D_ + 3] * p8 + (double)a[D_ + 4] * p16;
      long long h = (long long)floor(td);
      ((int*)ws)[2304 + o] = (int)((h % TBL + TBL) % TBL);
    }
  } else {
    // ---- wprep: bf16-convert ALL kernel rows ----
    int s = bx - 5248;
    uint* Wc = (uint*)((char*)ws + 16384);
    const float* src = kern + (size_t)s * D_;
    for (int e = t; e < 1152; e += 256) {
      uint lo = f2bf(src[2 * e]);
      uint hi = f2bf(src[2 * e + 1]);
      Wc[(size_t)s * 1152 + e] = lo | (hi << 16);
    }
  }
}

// ---------- Kernel R: qhash (reduce partials) + select, one block ----------
__global__ __launch_bounds__(512) void k_route(const float* __restrict__ a,
                                               float* __restrict__ ws) {
  int t = threadIdx.x;
  const float* P = ws + P_OFF;
  __shared__ double sh[8], sh2[8];
  __shared__ int shq, c1, c2;
  double sd = 0.0, sq = 0.0;
  if (t < 256) {  // identical summation order to the old 256-thread k_qhash
    for (int d = t; d < D_; d += 256) {
      float v = fmaxf(fmaxf(P[d], P[2304 + d]), fmaxf(P[4608 + d], P[6912 + d]));
      if ((d >> 8) != 4) v = fmaxf(v, 0.0f);  // padding zeros, non-center taps
      double dv = (double)v;
      sd += (double)a[d] * dv;
      sq += dv * dv;
    }
    for (int o = 32; o; o >>= 1) {
      sd += __shfl_down(sd, o, 64);
      sq += __shfl_down(sq, o, 64);
    }
    if ((t & 63) == 0) { sh[t >> 6] = sd; sh2[t >> 6] = sq; }
  }
  __syncthreads();
  if (t == 0) {
    double td = 0, tq = 0;
    for (int w = 0; w < 4; w++) { td += sh[w]; tq += sh2[w]; }
    double dot = td / sqrt(tq);
    dot += 0.5 * ((double)a[D_] + (double)a[D_ + 1] + (double)a[D_ + 2] +
                  (double)a[D_ + 3] + (double)a[D_ + 4]);
    long long h = (long long)floor(dot);
    int q = (int)((h % TBL + TBL) % TBL);
    ((int*)ws)[2816] = q;
    shq = q;
    c1 = 0; c2 = 0;
  }
  __syncthreads();
  // ---- select: active + inactive lists ----
  int* hashk = (int*)ws + 2304;
  int* cntp = (int*)ws + 2817;
  float* scalep = ws + 2818;
  int* active = (int*)ws + 2819;
  int* inact = (int*)ws + 3331;
  int q = shq;
  bool m = (hashk[t] == q);
  if (m) active[atomicAdd(&c1, 1)] = t;
  else   inact[atomicAdd(&c2, 1)] = t;
  __syncthreads();
  int c = c1;
  if (c == 0) active[t] = t;  // fallback: all channels, scale 1
  if (t == 0) {
    if (c > 0) { *cntp = c; *scalep = 512.0f / (float)c; }
    else       { *cntp = 512; *scalep = 1.0f; }
  }
}

#define XSTR 40      // ushorts per X position row (32 used + 8 pad)
#define XSTRIDE 40   // (fallback kernel)
#define ASTRIDE 104  // (fallback kernel)

// ---------- Kernel E5: A-direct MFMA conv ----------
// LDS-BW analysis (R3 post-mortem): 11 ds_read_b128/wave/phase = ~700 cyc/CU
// vs 272 cyc MFMA -> 39% MfmaUtil cap. Fix: A frags load global->VGPR directly
// (Wc is 2.36 MB, L2-resident; per-lane 16 B of row active[slot], 1-phase-ahead
// double buffer). LDS/phase/wave drops 14.25->8 KB; barriers drop 72->8 (X
// buffers are disjoint within a cc-chunk). Accumulation order unchanged.
__global__ __launch_bounds__(256, 2) void k_convx(const float* __restrict__ bias,
                                                  const float* __restrict__ ws,
                                                  float* __restrict__ out) {
  const int* iws = (const int*)ws;
  int cnt = iws[2817];
  int octile = blockIdx.y;
  int rt = blockIdx.x;          // image rows 4rt..4rt+3
  int n = blockIdx.z;
  int t = threadIdx.x;

  // ---- bias fill for this block's inactive slots (none when cnt==512) ----
  {
    int base = octile * 128;
    int lo = base < cnt ? cnt : base;
    int hi = base + 128;
    if (lo < hi) {
      const int* inact = iws + 3331;
      size_t nbase = (size_t)n * OUT_C * HW;
      int nin = hi - lo;
      for (int e = t; e < nin * 56; e += 256) {
        int j = e / 56, f = e - j * 56;
        int oc = inact[lo - cnt + j];
        float bv = bias[oc];
        ((float4*)out)[(nbase + (size_t)oc * HW + rt * 224) / 4 + f] =
            make_float4(bv, bv, bv, bv);
      }
    }
    if (base >= cnt) return;
  }

  float sc = ws[2818];
  const int* active = iws + 2819;
  const char* Wcb = (const char*)ws + 16384;
  const ushort* xb = (const ushort*)((const char*)ws + XB_OFF);

  int lane = t & 63, wid = t >> 6;
  int quad = lane >> 4, l16 = lane & 15;
  int ochalf = wid & 1, pxhalf = wid >> 1;

  __shared__ __align__(16) ushort X_lds[2][348 * XSTR];  // 2 x 27840 B

  int pbase[7];
#pragma unroll
  for (int b = 0; b < 7; b++) {
    int pxl = pxhalf * 112 + b * 16 + l16;
    int rl = pxl / 56;
    int col = pxl - rl * 56;
    pbase[b] = ((rl + 1) * 58 + (col + 1)) * XSTR;
  }

  // A-direct byte offsets: lane l16 -> oc row (via active[]), quad -> 16B chunk
  uint woff[4];
#pragma unroll
  for (int a = 0; a < 4; a++) {
    int slot = octile * 128 + ochalf * 64 + a * 16 + l16;
    int aoc = (slot < cnt) ? active[slot] : 0;  // clamp: garbage rows discarded
    woff[a] = (uint)aoc * 4608u + (uint)quad * 16u;
  }

  const size_t CGS = (size_t)16 * 58 * XB_ROW;
  const ushort* xsrc = xb + (size_t)(n * 58 + rt * 4) * XB_ROW;

  f32x4 acc[4][7];
#pragma unroll
  for (int a = 0; a < 4; a++)
#pragma unroll
    for (int b = 0; b < 7; b++) acc[a][b] = (f32x4){0.f, 0.f, 0.f, 0.f};

  uint4 curA[4], nA[4];
  uint4 xh; int xhj = 0; bool xhv = false;

  // prologue: A(phase 0) -> regs, X(cc=0) -> LDS
  {
#pragma unroll
    for (int a = 0; a < 4; a++)
      curA[a] = *(const uint4*)(Wcb + woff[a]);
    for (int j = t; j < 1392; j += 256)
      *(uint4*)&X_lds[0][(j >> 2) * XSTR + (j & 3) * 8] =
          *(const uint4*)(xsrc + (size_t)j * 8);
  }
  __syncthreads();

  for (int cc = 0; cc < 8; ++cc) {
    const int xc = cc & 1;
#pragma unroll
    for (int tap = 0; tap < 9; ++tap) {
      const int tapn = (tap + 1) % 9;       // compile-time
      const int ccn = cc + (tap + 1) / 9;   // runtime
      const bool havenext = !(cc == 7 && tap == 8);
      // issue A(g+1) -> regs (hides L2 latency under this phase's MFMAs)
      if (havenext) {
        uint go = (uint)(tapn * 512) + (uint)ccn * 64u;
#pragma unroll
        for (int a = 0; a < 4; a++)
          nA[a] = *(const uint4*)(Wcb + woff[a] + go);
      }
      // issue X(cc+1) part 'tap' (landed next phase)
      const bool xpf = (tap < 6) && (cc < 7) && (t < 232);
      uint4 xv; int xj = tap * 232 + t;
      if (xpf)
        xv = *(const uint4*)(xsrc + (size_t)(cc + 1) * CGS + (size_t)xj * 8);

      // ---- 28 MFMAs: A from regs, X from LDS ----
      const int kh = tap / 3, kw = tap - kh * 3;
      const int poff = ((kh - 1) * 58 + (kw - 1)) * XSTR + quad * 8;
      __builtin_amdgcn_s_setprio(1);
#pragma unroll
      for (int b = 0; b < 7; b++) {
        union { uint4 u; bf16x8 v; } cv;
        cv.u = *(const uint4*)&X_lds[xc][pbase[b] + poff];
        bf16x8 xf = cv.v;
#pragma unroll
        for (int a = 0; a < 4; a++) {
          union { uint4 u; bf16x8 v; } av;
          av.u = curA[a];
          acc[a][b] = __builtin_amdgcn_mfma_f32_16x16x32_bf16(av.v, xf,
                                                              acc[a][b], 0, 0, 0);
        }
      }
      __builtin_amdgcn_s_setprio(0);

      // land X part held from previous phase (targets idle buffer xc^1)
      if (xhv)
        *(uint4*)&X_lds[xc ^ 1][(xhj >> 2) * XSTR + (xhj & 3) * 8] = xh;
      xh = xv; xhj = xj; xhv = xpf;
      if (havenext) {
#pragma unroll
        for (int a = 0; a < 4; a++) curA[a] = nA[a];
      }
    }
    __syncthreads();  // cc boundary: all reads of X_lds[xc] done before cc+1 writes it
  }

  // epilogue: C[m=quad*4+r (oc), n=l16 (px)]
  size_t nbase = (size_t)n * OUT_C * HW;
#pragma unroll
  for (int a = 0; a < 4; a++) {
#pragma unroll
    for (int r = 0; r < 4; r++) {
      int slot = octile * 128 + ochalf * 64 + a * 16 + quad * 4 + r;
      if (slot < cnt) {
        int oc = active[slot];
        float bv = bias[oc];
        size_t obase = nbase + (size_t)oc * HW + rt * 224 + pxhalf * 112 + l16;
#pragma unroll
        for (int b = 0; b < 7; b++)
          out[obase + b * 16] = acc[a][b][r] * sc + bv;
      }
    }
  }
}

// ================= FALLBACK PATH (ws too small) =================

__global__ __launch_bounds__(256) void k_chanmax(const float* __restrict__ x,
                                                 float* __restrict__ ws) {
  int c = blockIdx.x, t = threadIdx.x;
  float m[3][3];
#pragma unroll
  for (int i = 0; i < 3; i++)
#pragma unroll
    for (int j = 0; j < 3; j++) m[i][j] = -INFINITY;
  for (int e = t; e < 16 * HW; e += 256) {
    int n = e / HW;
    int rem = e - n * HW;
    int r = rem / W_;
    int s = rem - r * W_;
    float v = x[(size_t)(n * IN_C + c) * HW + rem];
    bool rc[3] = { r <= 54, true, r >= 1 };
    bool sc[3] = { s <= 54, true, s >= 1 };
#pragma unroll
    for (int i = 0; i < 3; i++)
#pragma unroll
      for (int j = 0; j < 3; j++)
        if (rc[i] && sc[j]) m[i][j] = fmaxf(m[i][j], v);
  }
#pragma unroll
  for (int i = 0; i < 3; i++)
#pragma unroll
    for (int j = 0; j < 3; j++)
      for (int o = 32; o; o >>= 1)
        m[i][j] = fmaxf(m[i][j], __shfl_down(m[i][j], o, 64));
  __shared__ float red[4][9];
  int lane = t & 63, wid = t >> 6;
  if (lane == 0) {
#pragma unroll
    for (int i = 0; i < 3; i++)
#pragma unroll
      for (int j = 0; j < 3; j++) red[wid][i * 3 + j] = m[i][j];
  }
  __syncthreads();
  if (t < 9) {
    float v = fmaxf(fmaxf(red[0][t], red[1][t]), fmaxf(red[2][t], red[3][t]));
    int i = t / 3, j = t - i * 3;
    if (i != 1 || j != 1) v = fmaxf(v, 0.0f);
    ws[(size_t)t * IN_C + c] = v;
  }
}

__global__ __launch_bounds__(256) void k_qhash(const float* __restrict__ a,
                                               float* __restrict__ ws) {
  const float* max_row = ws;
  int t = threadIdx.x;
  double sd = 0.0, sq = 0.0;
  for (int d = t; d < D_; d += 256) {
    double v = (double)max_row[d];
    sd += (double)a[d] * v;
    sq += v * v;
  }
  __shared__ double sh[8], sh2[8];
  int lane = t & 63, wid = t >> 6;
  for (int o = 32; o; o >>= 1) {
    sd += __shfl_down(sd, o, 64);
    sq += __shfl_down(sq, o, 64);
  }
  if (lane == 0) { sh[wid] = sd; sh2[wid] = sq; }
  __syncthreads();
  if (t == 0) {
    double td = 0, tq = 0;
    for (int w = 0; w < 4; w++) { td += sh[w]; tq += sh2[w]; }
    double dot = td / sqrt(tq);
    dot += 0.5 * ((double)a[D_] + (double)a[D_ + 1] + (double)a[D_ + 2] +
                  (double)a[D_ + 3] + (double)a[D_ + 4]);
    long long h = (long long)floor(dot);
    ((int*)ws)[2816] = (int)((h % TBL + TBL) % TBL);
  }
}

__global__ __launch_bounds__(256) void k_khash(const float* __restrict__ kern,
                                               const float* __restrict__ a,
                                               float* __restrict__ ws) {
  int o = blockIdx.x, t = threadIdx.x;
  const float* kr = kern + (size_t)o * D_;
  double sd = 0, sn = 0;
  for (int d = t; d < D_; d += 256) {
    double w = (double)kr[d];
    sd += (double)a[d] * w;
    sn += w * w;
  }
  __shared__ double sh[8], sh2[8];
  int lane = t & 63, wid = t >> 6;
  for (int off = 32; off; off >>= 1) {
    sd += __shfl_down(sd, off, 64);
    sn += __shfl_down(sn, off, 64);
  }
  if (lane == 0) { sh[wid] = sd; sh2[wid] = sn; }
  __syncthreads();
  if (t == 0) {
    double td = 0, tn = 0;
    for (int w = 0; w < 4; w++) { td += sh[w]; tn += sh2[w]; }
    double p1 = tn, p2 = p1 * p1, p4 = p2 * p2, p8 = p4 * p4, p16 = p8 * p8;
    td += (double)a[D_] * p1 + (double)a[D_ + 1] * p2 + (double)a[D_ + 2] * p4 +
          (double)a[D_ + 3] * p8 + (double)a[D_ + 4] * p16;
    long long h = (long long)floor(td);
    ((int*)ws)[2304 + o] = (int)((h % TBL + TBL) % TBL);
  }
}

__global__ __launch_bounds__(512) void k_select(float* __restrict__ ws) {
  int t = threadIdx.x;
  int* hashk = (int*)ws + 2304;
  int* qidx = (int*)ws + 2816;
  int* cntp = (int*)ws + 2817;
  float* scalep = ws + 2818;
  int* active = (int*)ws + 2819;
  int* flags = (int*)ws + 3331;
  __shared__ int cnt;
  if (t == 0) cnt = 0;
  active[t] = 0;
  __syncthreads();
  int q = *qidx;
  bool m = (hashk[t] == q);
  if (m) {
    int p = atomicAdd(&cnt, 1);
    active[p] = t;
  }
  __syncthreads();
  int c = cnt;
  flags[t] = (c == 0) ? 1 : (m ? 1 : 0);
  if (c == 0) active[t] = t;
  if (t == 0) {
    if (c > 0) { *cntp = c; *scalep = 512.0f / (float)c; }
    else       { *cntp = 512; *scalep = 1.0f; }
  }
}

__global__ __launch_bounds__(256) void k_prep(const float* __restrict__ kern,
                                              float* __restrict__ ws) {
  const int* iws = (const int*)ws;
  int cnt = iws[2817];
  const int* active = iws + 2819;
  ushort* Wc = (ushort*)((char*)ws + 16384);
  int s = blockIdx.x, t = threadIdx.x;
  if (s < cnt) {
    int oc = active[s];
    const float* src = kern + (size_t)oc * D_;
    for (int e = t; e < D_; e += 256) Wc[(size_t)s * D_ + e] = f2bf(src[e]);
  } else {
    for (int e = t; e < D_; e += 256) Wc[(size_t)s * D_ + e] = 0;
  }
}

__global__ __launch_bounds__(256) void k_biasfill(const float* __restrict__ bias,
                                                  const float* __restrict__ ws,
                                                  float* __restrict__ out) {
  const int* flags = (const int*)ws + 3331;
  const int total4 = 16 * OUT_C * HW / 4;
  int stride = gridDim.x * blockDim.x;
  for (int i = blockIdx.x * blockDim.x + threadIdx.x; i < total4; i += stride) {
    int o = (i / 784) & (OUT_C - 1);
    if (!flags[o]) {
      float b = bias[o];
      ((float4*)out)[i] = make_float4(b, b, b, b);
    }
  }
}

__global__ __launch_bounds__(256, 2) void k_conv(const float* __restrict__ x,
                                                 const float* __restrict__ bias,
                                                 const float* __restrict__ ws,
                                                 float* __restrict__ out) {
  const int* iws = (const int*)ws;
  int cnt = iws[2817];
  int octile = blockIdx.y;
  if (octile * 128 >= cnt) return;
  float sc = ws[2818];
  const int* active = iws + 2819;
  const ushort* Wc = (const ushort*)((const char*)ws + 16384);
  int rt = blockIdx.x;
  int n = blockIdx.z;
  int t = threadIdx.x;
  int lane = t & 63, wid = t >> 6;
  int quad = lane >> 4, l16 = lane & 15;
  int ochalf = wid & 1, pxhalf = wid >> 1;
  __shared__ __align__(16) ushort X_lds[348 * XSTRIDE];
  __shared__ __align__(16) ushort A_lds[128 * ASTRIDE];
  const float* xin = x + (size_t)n * IN_C * HW;
  int pbase[7];
#pragma unroll
  for (int b = 0; b < 7; b++) {
    int pxl = pxhalf * 112 + b * 16 + l16;
    int rl = pxl / 56;
    int col = pxl - rl * 56;
    pbase[b] = ((rl + 1) * 58 + (col + 1)) * XSTRIDE;
  }
  f32x4 acc[4][7];
#pragma unroll
  for (int a = 0; a < 4; a++)
#pragma unroll
    for (int b = 0; b < 7; b++) acc[a][b] = (f32x4){0.f, 0.f, 0.f, 0.f};
  for (int cc = 0; cc < 8; ++cc) {
    int c0 = cc * 32;
    __syncthreads();
    for (int e = t; e < 1392; e += 256) {
      int q = e / 348;
      int p = e - q * 348;
      int rl = p / 58;
      int cp = p - rl * 58;
      int y = rt * 4 - 1 + rl;
      int xx = cp - 1;
      float vv[8];
      if ((unsigned)y < 56u && (unsigned)xx < 56u) {
        const float* src = xin + (size_t)(c0 + q * 8) * HW + y * W_ + xx;
#pragma unroll
        for (int k = 0; k < 8; k++) vv[k] = src[(size_t)k * HW];
      } else {
#pragma unroll
        for (int k = 0; k < 8; k++) vv[k] = 0.f;
      }
      uint4 pk;
      pk.x = (uint)f2bf(vv[0]) | ((uint)f2bf(vv[1]) << 16);
      pk.y = (uint)f2bf(vv[2]) | ((uint)f2bf(vv[3]) << 16);
      pk.z = (uint)f2bf(vv[4]) | ((uint)f2bf(vv[5]) << 16);
      pk.w = (uint)f2bf(vv[6]) | ((uint)f2bf(vv[7]) << 16);
      *(uint4*)&X_lds[p * XSTRIDE + q * 8] = pk;
    }
    for (int kh = 0; kh < 3; ++kh) {
      __syncthreads();
      for (int e = t; e < 1536; e += 256) {
        int oc = e / 12;
        int seg = e - oc * 12;
        int tl = seg >> 2, q = seg & 3;
        uint4 v = *(const uint4*)(Wc + (size_t)(octile * 128 + oc) * D_ +
                                  (kh * 3 + tl) * IN_C + c0 + q * 8);
        *(uint4*)&A_lds[oc * ASTRIDE + tl * 32 + q * 8] = v;
      }
      __syncthreads();
      int di = kh - 1;
#pragma unroll
      for (int djj = 0; djj < 3; ++djj) {
        int poff = (di * 58 + (djj - 1)) * XSTRIDE + quad * 8;
        bf16x8 bfr[7];
#pragma unroll
        for (int b = 0; b < 7; b++) {
          union { uint4 u; bf16x8 v; } cv;
          cv.u = *(const uint4*)&X_lds[pbase[b] + poff];
          bfr[b] = cv.v;
        }
#pragma unroll
        for (int a = 0; a < 4; a++) {
          union { uint4 u; bf16x8 v; } cv;
          cv.u = *(const uint4*)&A_lds[(ochalf * 64 + a * 16 + l16) * ASTRIDE +
                                       djj * 32 + quad * 8];
          bf16x8 af = cv.v;
#pragma unroll
          for (int b = 0; b < 7; b++)
            acc[a][b] = __builtin_amdgcn_mfma_f32_16x16x32_bf16(af, bfr[b],
                                                                acc[a][b], 0, 0, 0);
        }
      }
    }
  }
  size_t nbase = (size_t)n * OUT_C * HW;
#pragma unroll
  for (int a = 0; a < 4; a++) {
#pragma unroll
    for (int r = 0; r < 4; r++) {
      int slot = octile * 128 + ochalf * 64 + a * 16 + quad * 4 + r;
      if (slot < cnt) {
        int oc = active[slot];
        float bv = bias[oc];
        size_t obase = nbase + (size_t)oc * HW + rt * 224 + pxhalf * 112 + l16;
#pragma unroll
        for (int b = 0; b < 7; b++)
          out[obase + b * 16] = acc[a][b][r] * sc + bv;
      }
    }
  }
}

extern "C" void kernel_launch(void* const* d_in, const int* in_sizes, int n_in,
                              void* d_out, int out_size, void* d_ws, size_t ws_size,
                              hipStream_t stream) {
  const float* x    = (const float*)d_in[0];
  const float* kern = (const float*)d_in[1];
  const float* bias = (const float*)d_in[2];
  const float* a    = (const float*)d_in[3];
  float* out = (float*)d_out;
  float* ws  = (float*)d_ws;

  const size_t need = 29933568ULL + 4 * 2304 * 4;  // Xb end + partials = 29,970,432

  if (ws_size >= need) {
    k_setup<<<dim3(5760), dim3(256), 0, stream>>>(x, kern, a, ws);
    k_route<<<dim3(1), dim3(512), 0, stream>>>(a, ws);
    k_convx<<<dim3(14, 4, 16), dim3(256), 0, stream>>>(bias, ws, out);
  } else {
    k_chanmax<<<dim3(IN_C), dim3(256), 0, stream>>>(x, ws);
    k_qhash<<<dim3(1), dim3(256), 0, stream>>>(a, ws);
    k_khash<<<dim3(OUT_C), dim3(256), 0, stream>>>(kern, a, ws);
    k_select<<<dim3(1), dim3(512), 0, stream>>>(ws);
    k_prep<<<dim3(OUT_C), dim3(256), 0, stream>>>(kern, ws);
    k_biasfill<<<dim3(4096), dim3(256), 0, stream>>>(bias, ws, out);
    k_conv<<<dim3(14, 4, 16), dim3(256), 0, stream>>>(x, bias, ws, out);
  }
}

// Round 5
// 323.048 us; speedup vs baseline: 1.0529x; 1.0529x over previous
//
#include <hip/hip_runtime.h>
#include <math.h>

#define IN_C   256
#define OUT_C  512
#define HW     3136
#define W_     56
#define D_     2304
#define TBL    16

// ws layout (4-byte units):
// [0,2304)      max_row (float)           (fallback path only)
// [2304,2816)   hashk (int)
// [2816]        qidx (int)
// [2817]        count_eff (int)
// [2818]        scale_mul (float)
// [2819,3331)   active (int)
// [3331,3843)   inact (int, fast path) / flags (fallback)
// byte 16384+   Wc: bf16 weights [512][2304] (fast path: ALL rows; conv uses active[])
// byte 2375680+ Xb: bf16 padded x [cg=8][n=16][yp=58][wp=58][c=32]
// byte 29933568+ P: chanmax partials [part=4][tap=9][c=256] float (fast path)

#define XB_OFF 2375680ULL
#define XB_ROW 1856            // ushorts per (cg,n,yp) row: 58*32
#define P_OFF  7483392         // float index of partials (byte 29933568)

typedef __attribute__((ext_vector_type(8))) __bf16 bf16x8;
typedef __attribute__((ext_vector_type(4))) float f32x4;

__device__ __forceinline__ ushort f2bf(float f) {
  uint b = __float_as_uint(f);
  b = b + 0x7FFFu + ((b >> 16) & 1u);
  return (ushort)(b >> 16);
}

// ================= FAST PATH =================

// ---------- Kernel S: fused setup ----------
// blocks [0,3712): xprep | [3712,4736): chanmax partials | [4736,5248): khash
// [5248,5760): wprep — bf16-convert ALL 512 kernel rows.
__global__ __launch_bounds__(256) void k_setup(const float* __restrict__ x,
                                               const float* __restrict__ kern,
                                               const float* __restrict__ a,
                                               float* __restrict__ ws) {
  __shared__ __align__(16) float smem[64 * 57];  // 14592 B, aliased per path
  int bx = blockIdx.x, t = threadIdx.x;

  if (bx < 3712) {
    // ---- xprep: fp32 NCHW -> bf16 padded [cg][n][58][58][32], one 64-ch chunk ----
    int c0i = bx & 3;             // 64-channel chunk
    int n = (bx >> 2) & 15;
    int yp = bx >> 6;             // 0..57
    int c0 = c0i * 64, cgbase = c0i * 2;
    ushort* xb = (ushort*)((char*)ws + XB_OFF);
    const size_t CGS = (size_t)16 * 58 * XB_ROW;
    size_t rb0 = (size_t)(n * 58 + yp) * XB_ROW;
    uint4 z4 = make_uint4(0u, 0u, 0u, 0u);

    if (yp == 0 || yp == 57) {    // border rows: zeros for this block's 2 cgs
      for (int e = t; e < 464; e += 256) {
        int cg_l = e / 232, k = e - cg_l * 232;
        *(uint4*)&xb[rb0 + (size_t)(cgbase + cg_l) * CGS + (size_t)k * 8] = z4;
      }
      return;
    }
    if (t < 16) {                 // column borders wp = 0, 57
      int cg_l = t >> 3, r = t & 7;
      int wp = (r >> 2) ? 57 : 0, oct = r & 3;
      *(uint4*)&xb[rb0 + (size_t)(cgbase + cg_l) * CGS + wp * 32 + oct * 8] = z4;
    }
    int y = yp - 1;
    float* Lf = smem;             // [64][57]
    for (int e = t; e < 3584; e += 256) {
      int ci = e / 56, w = e - ci * 56;
      Lf[ci * 57 + w] = x[(size_t)(n * 256 + c0 + ci) * 3136 + y * 56 + w];
    }
    __syncthreads();
    for (int e = t; e < 448; e += 256) {
      int w = e >> 3, cg_l = (e >> 2) & 1, oct = e & 3;
      int cb = cg_l * 32 + oct * 8;
      uint pk[4];
#pragma unroll
      for (int k = 0; k < 4; k++) {
        uint lo = f2bf(Lf[(cb + 2 * k) * 57 + w]);
        uint hi = f2bf(Lf[(cb + 2 * k + 1) * 57 + w]);
        pk[k] = lo | (hi << 16);
      }
      *(uint4*)&xb[rb0 + (size_t)(cgbase + cg_l) * CGS + (w + 1) * 32 + oct * 8] =
          make_uint4(pk[0], pk[1], pk[2], pk[3]);
    }
  } else if (bx < 4736) {
    // ---- chanmax partial: 4 blocks/channel, 4 images each ----
    int idx = bx - 3712;
    int c = idx & 255, part = idx >> 8;
    float m[3][3];
#pragma unroll
    for (int i = 0; i < 3; i++)
#pragma unroll
      for (int j = 0; j < 3; j++) m[i][j] = -INFINITY;
    for (int e = t; e < 4 * HW; e += 256) {
      int nl = e / HW;
      int rem = e - nl * HW;
      int r = rem / W_;
      int s = rem - r * W_;
      float v = x[(size_t)((part * 4 + nl) * IN_C + c) * HW + rem];
      bool rc[3] = { r <= 54, true, r >= 1 };
      bool sc[3] = { s <= 54, true, s >= 1 };
#pragma unroll
      for (int i = 0; i < 3; i++)
#pragma unroll
        for (int j = 0; j < 3; j++)
          if (rc[i] && sc[j]) m[i][j] = fmaxf(m[i][j], v);
    }
#pragma unroll
    for (int i = 0; i < 3; i++)
#pragma unroll
      for (int j = 0; j < 3; j++)
        for (int o = 32; o; o >>= 1)
          m[i][j] = fmaxf(m[i][j], __shfl_down(m[i][j], o, 64));
    float* red = smem;            // [4][9]
    int lane = t & 63, wid = t >> 6;
    if (lane == 0) {
#pragma unroll
      for (int i = 0; i < 3; i++)
#pragma unroll
        for (int j = 0; j < 3; j++) red[wid * 9 + i * 3 + j] = m[i][j];
    }
    __syncthreads();
    if (t < 9) {
      float v = fmaxf(fmaxf(red[0 * 9 + t], red[1 * 9 + t]),
                      fmaxf(red[2 * 9 + t], red[3 * 9 + t]));
      ws[P_OFF + (size_t)part * 2304 + (size_t)t * IN_C + c] = v;  // no 0-cap here
    }
  } else if (bx < 5248) {
    // ---- khash: per-kernel-row hash ----
    int o = bx - 4736;
    const float* kr = kern + (size_t)o * D_;
    double sd = 0, sn = 0;
    for (int d = t; d < D_; d += 256) {
      double w = (double)kr[d];
      sd += (double)a[d] * w;
      sn += w * w;
    }
    double* sh = (double*)smem;
    double* sh2 = sh + 8;
    int lane = t & 63, wid = t >> 6;
    for (int off = 32; off; off >>= 1) {
      sd += __shfl_down(sd, off, 64);
      sn += __shfl_down(sn, off, 64);
    }
    if (lane == 0) { sh[wid] = sd; sh2[wid] = sn; }
    __syncthreads();
    if (t == 0) {
      double td = 0, tn = 0;
      for (int w = 0; w < 4; w++) { td += sh[w]; tn += sh2[w]; }
      double p1 = tn, p2 = p1 * p1, p4 = p2 * p2, p8 = p4 * p4, p16 = p8 * p8;
      td += (double)a[D_] * p1 + (double)a[D_ + 1] * p2 + (double)a[D_ + 2] * p4 +
            (double)a[D_ + 3] * p8 + (double)a[D_ + 4] * p16;
      long long h = (long long)floor(td);
      ((int*)ws)[2304 + o] = (int)((h % TBL + TBL) % TBL);
    }
  } else {
    // ---- wprep: bf16-convert ALL kernel rows ----
    int s = bx - 5248;
    uint* Wc = (uint*)((char*)ws + 16384);
    const float* src = kern + (size_t)s * D_;
    for (int e = t; e < 1152; e += 256) {
      uint lo = f2bf(src[2 * e]);
      uint hi = f2bf(src[2 * e + 1]);
      Wc[(size_t)s * 1152 + e] = lo | (hi << 16);
    }
  }
}

// ---------- Kernel R: qhash (reduce partials) + select, one block ----------
__global__ __launch_bounds__(512) void k_route(const float* __restrict__ a,
                                               float* __restrict__ ws) {
  int t = threadIdx.x;
  const float* P = ws + P_OFF;
  __shared__ double sh[8], sh2[8];
  __shared__ int shq, c1, c2;
  double sd = 0.0, sq = 0.0;
  if (t < 256) {  // identical summation order to the old 256-thread k_qhash
    for (int d = t; d < D_; d += 256) {
      float v = fmaxf(fmaxf(P[d], P[2304 + d]), fmaxf(P[4608 + d], P[6912 + d]));
      if ((d >> 8) != 4) v = fmaxf(v, 0.0f);  // padding zeros, non-center taps
      double dv = (double)v;
      sd += (double)a[d] * dv;
      sq += dv * dv;
    }
    for (int o = 32; o; o >>= 1) {
      sd += __shfl_down(sd, o, 64);
      sq += __shfl_down(sq, o, 64);
    }
    if ((t & 63) == 0) { sh[t >> 6] = sd; sh2[t >> 6] = sq; }
  }
  __syncthreads();
  if (t == 0) {
    double td = 0, tq = 0;
    for (int w = 0; w < 4; w++) { td += sh[w]; tq += sh2[w]; }
    double dot = td / sqrt(tq);
    dot += 0.5 * ((double)a[D_] + (double)a[D_ + 1] + (double)a[D_ + 2] +
                  (double)a[D_ + 3] + (double)a[D_ + 4]);
    long long h = (long long)floor(dot);
    int q = (int)((h % TBL + TBL) % TBL);
    ((int*)ws)[2816] = q;
    shq = q;
    c1 = 0; c2 = 0;
  }
  __syncthreads();
  // ---- select: active + inactive lists ----
  int* hashk = (int*)ws + 2304;
  int* cntp = (int*)ws + 2817;
  float* scalep = ws + 2818;
  int* active = (int*)ws + 2819;
  int* inact = (int*)ws + 3331;
  int q = shq;
  bool m = (hashk[t] == q);
  if (m) active[atomicAdd(&c1, 1)] = t;
  else   inact[atomicAdd(&c2, 1)] = t;
  __syncthreads();
  int c = c1;
  if (c == 0) active[t] = t;  // fallback: all channels, scale 1
  if (t == 0) {
    if (c > 0) { *cntp = c; *scalep = 512.0f / (float)c; }
    else       { *cntp = 512; *scalep = 1.0f; }
  }
}

#define XSTR 40      // ushorts per X position row (32 used + 8 pad)
#define XSTRIDE 40   // (fallback kernel)
#define ASTRIDE 104  // (fallback kernel)

// ---------- Kernel E6: big-M wave tile (128oc x 112px), 1 block/CU ----------
// R4 post-mortem: LDS read BW is the binding limit (272 MFMA cyc vs 704 LDS cyc
// per CU-phase = the measured 39% MfmaUtil). Fix bytes/FLOP: wave tile 64x112
// (11 reads / 28 MFMAs) -> 128x112 (15 reads / 56 MFMAs), 1.47x less LDS/FLOP.
// Block = 128 oc x 448 px (8 image rows), 4 waves tiling px. acc[8][7] = 224
// VGPR -> __launch_bounds__(256,1) for the 512-reg budget; LDS 113 KB (X dbuf
// 2x46.4 KB 10-row halo + A dbuf 2x10 KB) -> 1 block/CU. Same proven 72-phase
// schedule: per-phase reg prefetch of A (this tap+1) and X (1/8 of cc+1, held
// one phase), land after MFMAs, one barrier. Accumulation order per (oc,px)
// unchanged (cc-major, tap-ordered) -> bitwise-identical output.
__global__ __launch_bounds__(256, 1) void k_convx(const float* __restrict__ bias,
                                                  const float* __restrict__ ws,
                                                  float* __restrict__ out) {
  const int* iws = (const int*)ws;
  int cnt = iws[2817];
  int octile = blockIdx.y;
  int rt = blockIdx.x;          // image rows 8rt..8rt+7
  int n = blockIdx.z;
  int t = threadIdx.x;

  // ---- bias fill for this block's inactive slots (none when cnt==512) ----
  {
    int base = octile * 128;
    int lo = base < cnt ? cnt : base;
    int hi = base + 128;
    if (lo < hi) {
      const int* inact = iws + 3331;
      size_t nbase = (size_t)n * OUT_C * HW;
      int nin = hi - lo;
      for (int e = t; e < nin * 112; e += 256) {
        int j = e / 112, f = e - j * 112;
        int oc = inact[lo - cnt + j];
        float bv = bias[oc];
        ((float4*)out)[(nbase + (size_t)oc * HW) / 4 + rt * 112 + f] =
            make_float4(bv, bv, bv, bv);
      }
    }
    if (base >= cnt) return;
  }

  float sc = ws[2818];
  const int* active = iws + 2819;
  const char* Wcb = (const char*)ws + 16384;
  const ushort* xb = (const ushort*)((const char*)ws + XB_OFF);

  int lane = t & 63, wid = t >> 6;   // wid = px-quarter (0..3)
  int quad = lane >> 4, l16 = lane & 15;

  __shared__ __align__(16) ushort X_lds[2][580 * XSTR];  // 2 x 46400 B
  __shared__ __align__(16) ushort A_lds[2][128 * XSTR];  // 2 x 10240 B

  // per-b px coords and X base addresses (center tap); wave owns px wid*112..+111
  int pbase[7];
#pragma unroll
  for (int b = 0; b < 7; b++) {
    int pxl = wid * 112 + b * 16 + l16;
    int rl = pxl / 56;                 // 0..7
    int col = pxl - rl * 56;
    pbase[b] = ((rl + 1) * 58 + (col + 1)) * XSTR;
  }

  // A staging: thread t handles chunks t and t+256 of 512 (128 rows x 4 chunks)
  int r0 = t >> 2;                     // row 0..63; second chunk -> row+64
  int slot0 = octile * 128 + r0;
  int slot1 = slot0 + 64;
  int aoc0 = (slot0 < cnt) ? active[slot0] : 0;
  int aoc1 = (slot1 < cnt) ? active[slot1] : 0;
  const char* Wr0 = Wcb + (size_t)aoc0 * 4608 + (t & 3) * 16;
  const char* Wr1 = Wcb + (size_t)aoc1 * 4608 + (t & 3) * 16;
  int aoff0 = r0 * XSTR + (t & 3) * 8;
  int aoff1 = (r0 + 64) * XSTR + (t & 3) * 8;

  const size_t CGS = (size_t)16 * 58 * XB_ROW;
  const ushort* xsrc = xb + (size_t)(n * 58 + rt * 8) * XB_ROW;  // 10 rows halo

  f32x4 acc[8][7];
#pragma unroll
  for (int a = 0; a < 8; a++)
#pragma unroll
    for (int b = 0; b < 7; b++) acc[a][b] = (f32x4){0.f, 0.f, 0.f, 0.f};

  uint4 xh0 = {}, xh1 = {};

  // prologue: A(phase 0) -> LDS, X(cc=0) -> LDS (2320 uint4)
  {
    uint4 a0 = *(const uint4*)Wr0;
    uint4 a1 = *(const uint4*)Wr1;
    *(uint4*)&A_lds[0][aoff0] = a0;
    *(uint4*)&A_lds[0][aoff1] = a1;
    for (int j = t; j < 2320; j += 256)
      *(uint4*)&X_lds[0][(j >> 2) * XSTR + (j & 3) * 8] =
          *(const uint4*)(xsrc + (size_t)j * 8);
  }
  __syncthreads();

  for (int cc = 0; cc < 8; ++cc) {
    const int xc = cc & 1;
#pragma unroll
    for (int tap = 0; tap < 9; ++tap) {
      const int cur = (cc + tap) & 1;       // phase parity (72 phases, 9 odd)
      const int tapn = (tap + 1) % 9;       // compile-time
      const int ccn = cc + (tap + 1) / 9;   // runtime
      const bool havenext = !(cc == 7 && tap == 8);
      // issue A(next phase) -> regs (latency hides under this phase's MFMAs)
      uint4 na0, na1;
      if (havenext) {
        int off = tapn * 512 + ccn * 64;
        na0 = *(const uint4*)(Wr0 + off);
        na1 = *(const uint4*)(Wr1 + off);
      }
      // issue X(cc+1) part 'tap' (290/tap over taps 0..7; landed next phase)
      const bool xi = (tap < 8) && (cc < 7);
      uint4 xv0, xv1;
      if (xi) {
        int xj = tap * 290 + t;
        xv0 = *(const uint4*)(xsrc + (size_t)(cc + 1) * CGS + (size_t)xj * 8);
        if (t < 34)
          xv1 = *(const uint4*)(xsrc + (size_t)(cc + 1) * CGS +
                                (size_t)(xj + 256) * 8);
      }

      // ---- 56 MFMAs: 7 X frags + 8 A frags from LDS ----
      const int kh = tap / 3, kw = tap - kh * 3;
      const int poff = ((kh - 1) * 58 + (kw - 1)) * XSTR + quad * 8;
      bf16x8 xf[7];
#pragma unroll
      for (int b = 0; b < 7; b++) {
        union { uint4 u; bf16x8 v; } cv;
        cv.u = *(const uint4*)&X_lds[xc][pbase[b] + poff];
        xf[b] = cv.v;
      }
      __builtin_amdgcn_s_setprio(1);
#pragma unroll
      for (int a = 0; a < 8; a++) {
        union { uint4 u; bf16x8 v; } av;
        av.u = *(const uint4*)&A_lds[cur][(a * 16 + l16) * XSTR + quad * 8];
        bf16x8 af = av.v;
#pragma unroll
        for (int b = 0; b < 7; b++)
          acc[a][b] = __builtin_amdgcn_mfma_f32_16x16x32_bf16(af, xf[b],
                                                              acc[a][b], 0, 0, 0);
      }
      __builtin_amdgcn_s_setprio(0);

      // land A(next phase) into the idle A buffer
      if (havenext) {
        *(uint4*)&A_lds[cur ^ 1][aoff0] = na0;
        *(uint4*)&A_lds[cur ^ 1][aoff1] = na1;
      }
      // land X part held from previous phase (targets idle buffer xc^1)
      if (tap >= 1 && cc < 7) {
        int hj = (tap - 1) * 290 + t;
        *(uint4*)&X_lds[xc ^ 1][(hj >> 2) * XSTR + (hj & 3) * 8] = xh0;
        if (t < 34) {
          int hj2 = hj + 256;
          *(uint4*)&X_lds[xc ^ 1][(hj2 >> 2) * XSTR + (hj2 & 3) * 8] = xh1;
        }
      }
      xh0 = xv0; xh1 = xv1;
      __syncthreads();
    }
  }

  // epilogue: C[m=quad*4+r (oc), n=l16 (px)]
  size_t nbase = (size_t)n * OUT_C * HW;
#pragma unroll
  for (int a = 0; a < 8; a++) {
#pragma unroll
    for (int r = 0; r < 4; r++) {
      int slot = octile * 128 + a * 16 + quad * 4 + r;
      if (slot < cnt) {
        int oc = active[slot];
        float bv = bias[oc];
        size_t obase = nbase + (size_t)oc * HW + rt * 448 + wid * 112 + l16;
#pragma unroll
        for (int b = 0; b < 7; b++)
          out[obase + b * 16] = acc[a][b][r] * sc + bv;
      }
    }
  }
}

// ================= FALLBACK PATH (ws too small) =================

__global__ __launch_bounds__(256) void k_chanmax(const float* __restrict__ x,
                                                 float* __restrict__ ws) {
  int c = blockIdx.x, t = threadIdx.x;
  float m[3][3];
#pragma unroll
  for (int i = 0; i < 3; i++)
#pragma unroll
    for (int j = 0; j < 3; j++) m[i][j] = -INFINITY;
  for (int e = t; e < 16 * HW; e += 256) {
    int n = e / HW;
    int rem = e - n * HW;
    int r = rem / W_;
    int s = rem - r * W_;
    float v = x[(size_t)(n * IN_C + c) * HW + rem];
    bool rc[3] = { r <= 54, true, r >= 1 };
    bool sc[3] = { s <= 54, true, s >= 1 };
#pragma unroll
    for (int i = 0; i < 3; i++)
#pragma unroll
      for (int j = 0; j < 3; j++)
        if (rc[i] && sc[j]) m[i][j] = fmaxf(m[i][j], v);
  }
#pragma unroll
  for (int i = 0; i < 3; i++)
#pragma unroll
    for (int j = 0; j < 3; j++)
      for (int o = 32; o; o >>= 1)
        m[i][j] = fmaxf(m[i][j], __shfl_down(m[i][j], o, 64));
  __shared__ float red[4][9];
  int lane = t & 63, wid = t >> 6;
  if (lane == 0) {
#pragma unroll
    for (int i = 0; i < 3; i++)
#pragma unroll
      for (int j = 0; j < 3; j++) red[wid][i * 3 + j] = m[i][j];
  }
  __syncthreads();
  if (t < 9) {
    float v = fmaxf(fmaxf(red[0][t], red[1][t]), fmaxf(red[2][t], red[3][t]));
    int i = t / 3, j = t - i * 3;
    if (i != 1 || j != 1) v = fmaxf(v, 0.0f);
    ws[(size_t)t * IN_C + c] = v;
  }
}

__global__ __launch_bounds__(256) void k_qhash(const float* __restrict__ a,
                                               float* __restrict__ ws) {
  const float* max_row = ws;
  int t = threadIdx.x;
  double sd = 0.0, sq = 0.0;
  for (int d = t; d < D_; d += 256) {
    double v = (double)max_row[d];
    sd += (double)a[d] * v;
    sq += v * v;
  }
  __shared__ double sh[8], sh2[8];
  int lane = t & 63, wid = t >> 6;
  for (int o = 32; o; o >>= 1) {
    sd += __shfl_down(sd, o, 64);
    sq += __shfl_down(sq, o, 64);
  }
  if (lane == 0) { sh[wid] = sd; sh2[wid] = sq; }
  __syncthreads();
  if (t == 0) {
    double td = 0, tq = 0;
    for (int w = 0; w < 4; w++) { td += sh[w]; tq += sh2[w]; }
    double dot = td / sqrt(tq);
    dot += 0.5 * ((double)a[D_] + (double)a[D_ + 1] + (double)a[D_ + 2] +
                  (double)a[D_ + 3] + (double)a[D_ + 4]);
    long long h = (long long)floor(dot);
    ((int*)ws)[2816] = (int)((h % TBL + TBL) % TBL);
  }
}

__global__ __launch_bounds__(256) void k_khash(const float* __restrict__ kern,
                                               const float* __restrict__ a,
                                               float* __restrict__ ws) {
  int o = blockIdx.x, t = threadIdx.x;
  const float* kr = kern + (size_t)o * D_;
  double sd = 0, sn = 0;
  for (int d = t; d < D_; d += 256) {
    double w = (double)kr[d];
    sd += (double)a[d] * w;
    sn += w * w;
  }
  __shared__ double sh[8], sh2[8];
  int lane = t & 63, wid = t >> 6;
  for (int off = 32; off; off >>= 1) {
    sd += __shfl_down(sd, off, 64);
    sn += __shfl_down(sn, off, 64);
  }
  if (lane == 0) { sh[wid] = sd; sh2[wid] = sn; }
  __syncthreads();
  if (t == 0) {
    double td = 0, tn = 0;
    for (int w = 0; w < 4; w++) { td += sh[w]; tn += sh2[w]; }
    double p1 = tn, p2 = p1 * p1, p4 = p2 * p2, p8 = p4 * p4, p16 = p8 * p8;
    td += (double)a[D_] * p1 + (double)a[D_ + 1] * p2 + (double)a[D_ + 2] * p4 +
          (double)a[D_ + 3] * p8 + (double)a[D_ + 4] * p16;
    long long h = (long long)floor(td);
    ((int*)ws)[2304 + o] = (int)((h % TBL + TBL) % TBL);
  }
}

__global__ __launch_bounds__(512) void k_select(float* __restrict__ ws) {
  int t = threadIdx.x;
  int* hashk = (int*)ws + 2304;
  int* qidx = (int*)ws + 2816;
  int* cntp = (int*)ws + 2817;
  float* scalep = ws + 2818;
  int* active = (int*)ws + 2819;
  int* flags = (int*)ws + 3331;
  __shared__ int cnt;
  if (t == 0) cnt = 0;
  active[t] = 0;
  __syncthreads();
  int q = *qidx;
  bool m = (hashk[t] == q);
  if (m) {
    int p = atomicAdd(&cnt, 1);
    active[p] = t;
  }
  __syncthreads();
  int c = cnt;
  flags[t] = (c == 0) ? 1 : (m ? 1 : 0);
  if (c == 0) active[t] = t;
  if (t == 0) {
    if (c > 0) { *cntp = c; *scalep = 512.0f / (float)c; }
    else       { *cntp = 512; *scalep = 1.0f; }
  }
}

__global__ __launch_bounds__(256) void k_prep(const float* __restrict__ kern,
                                              float* __restrict__ ws) {
  const int* iws = (const int*)ws;
  int cnt = iws[2817];
  const int* active = iws + 2819;
  ushort* Wc = (ushort*)((char*)ws + 16384);
  int s = blockIdx.x, t = threadIdx.x;
  if (s < cnt) {
    int oc = active[s];
    const float* src = kern + (size_t)oc * D_;
    for (int e = t; e < D_; e += 256) Wc[(size_t)s * D_ + e] = f2bf(src[e]);
  } else {
    for (int e = t; e < D_; e += 256) Wc[(size_t)s * D_ + e] = 0;
  }
}

__global__ __launch_bounds__(256) void k_biasfill(const float* __restrict__ bias,
                                                  const float* __restrict__ ws,
                                                  float* __restrict__ out) {
  const int* flags = (const int*)ws + 3331;
  const int total4 = 16 * OUT_C * HW / 4;
  int stride = gridDim.x * blockDim.x;
  for (int i = blockIdx.x * blockDim.x + threadIdx.x; i < total4; i += stride) {
    int o = (i / 784) & (OUT_C - 1);
    if (!flags[o]) {
      float b = bias[o];
      ((float4*)out)[i] = make_float4(b, b, b, b);
    }
  }
}

__global__ __launch_bounds__(256, 2) void k_conv(const float* __restrict__ x,
                                                 const float* __restrict__ bias,
                                                 const float* __restrict__ ws,
                                                 float* __restrict__ out) {
  const int* iws = (const int*)ws;
  int cnt = iws[2817];
  int octile = blockIdx.y;
  if (octile * 128 >= cnt) return;
  float sc = ws[2818];
  const int* active = iws + 2819;
  const ushort* Wc = (const ushort*)((const char*)ws + 16384);
  int rt = blockIdx.x;
  int n = blockIdx.z;
  int t = threadIdx.x;
  int lane = t & 63, wid = t >> 6;
  int quad = lane >> 4, l16 = lane & 15;
  int ochalf = wid & 1, pxhalf = wid >> 1;
  __shared__ __align__(16) ushort X_lds[348 * XSTRIDE];
  __shared__ __align__(16) ushort A_lds[128 * ASTRIDE];
  const float* xin = x + (size_t)n * IN_C * HW;
  int pbase[7];
#pragma unroll
  for (int b = 0; b < 7; b++) {
    int pxl = pxhalf * 112 + b * 16 + l16;
    int rl = pxl / 56;
    int col = pxl - rl * 56;
    pbase[b] = ((rl + 1) * 58 + (col + 1)) * XSTRIDE;
  }
  f32x4 acc[4][7];
#pragma unroll
  for (int a = 0; a < 4; a++)
#pragma unroll
    for (int b = 0; b < 7; b++) acc[a][b] = (f32x4){0.f, 0.f, 0.f, 0.f};
  for (int cc = 0; cc < 8; ++cc) {
    int c0 = cc * 32;
    __syncthreads();
    for (int e = t; e < 1392; e += 256) {
      int q = e / 348;
      int p = e - q * 348;
      int rl = p / 58;
      int cp = p - rl * 58;
      int y = rt * 4 - 1 + rl;
      int xx = cp - 1;
      float vv[8];
      if ((unsigned)y < 56u && (unsigned)xx < 56u) {
        const float* src = xin + (size_t)(c0 + q * 8) * HW + y * W_ + xx;
#pragma unroll
        for (int k = 0; k < 8; k++) vv[k] = src[(size_t)k * HW];
      } else {
#pragma unroll
        for (int k = 0; k < 8; k++) vv[k] = 0.f;
      }
      uint4 pk;
      pk.x = (uint)f2bf(vv[0]) | ((uint)f2bf(vv[1]) << 16);
      pk.y = (uint)f2bf(vv[2]) | ((uint)f2bf(vv[3]) << 16);
      pk.z = (uint)f2bf(vv[4]) | ((uint)f2bf(vv[5]) << 16);
      pk.w = (uint)f2bf(vv[6]) | ((uint)f2bf(vv[7]) << 16);
      *(uint4*)&X_lds[p * XSTRIDE + q * 8] = pk;
    }
    for (int kh = 0; kh < 3; ++kh) {
      __syncthreads();
      for (int e = t; e < 1536; e += 256) {
        int oc = e / 12;
        int seg = e - oc * 12;
        int tl = seg >> 2, q = seg & 3;
        uint4 v = *(const uint4*)(Wc + (size_t)(octile * 128 + oc) * D_ +
                                  (kh * 3 + tl) * IN_C + c0 + q * 8);
        *(uint4*)&A_lds[oc * ASTRIDE + tl * 32 + q * 8] = v;
      }
      __syncthreads();
      int di = kh - 1;
#pragma unroll
      for (int djj = 0; djj < 3; ++djj) {
        int poff = (di * 58 + (djj - 1)) * XSTRIDE + quad * 8;
        bf16x8 bfr[7];
#pragma unroll
        for (int b = 0; b < 7; b++) {
          union { uint4 u; bf16x8 v; } cv;
          cv.u = *(const uint4*)&X_lds[pbase[b] + poff];
          bfr[b] = cv.v;
        }
#pragma unroll
        for (int a = 0; a < 4; a++) {
          union { uint4 u; bf16x8 v; } cv;
          cv.u = *(const uint4*)&A_lds[(ochalf * 64 + a * 16 + l16) * ASTRIDE +
                                       djj * 32 + quad * 8];
          bf16x8 af = cv.v;
#pragma unroll
          for (int b = 0; b < 7; b++)
            acc[a][b] = __builtin_amdgcn_mfma_f32_16x16x32_bf16(af, bfr[b],
                                                                acc[a][b], 0, 0, 0);
        }
      }
    }
  }
  size_t nbase = (size_t)n * OUT_C * HW;
#pragma unroll
  for (int a = 0; a < 4; a++) {
#pragma unroll
    for (int r = 0; r < 4; r++) {
      int slot = octile * 128 + ochalf * 64 + a * 16 + quad * 4 + r;
      if (slot < cnt) {
        int oc = active[slot];
        float bv = bias[oc];
        size_t obase = nbase + (size_t)oc * HW + rt * 224 + pxhalf * 112 + l16;
#pragma unroll
        for (int b = 0; b < 7; b++)
          out[obase + b * 16] = acc[a][b][r] * sc + bv;
      }
    }
  }
}

extern "C" void kernel_launch(void* const* d_in, const int* in_sizes, int n_in,
                              void* d_out, int out_size, void* d_ws, size_t ws_size,
                              hipStream_t stream) {
  const float* x    = (const float*)d_in[0];
  const float* kern = (const float*)d_in[1];
  const float* bias = (const float*)d_in[2];
  const float* a    = (const float*)d_in[3];
  float* out = (float*)d_out;
  float* ws  = (float*)d_ws;

  const size_t need = 29933568ULL + 4 * 2304 * 4;  // Xb end + partials = 29,970,432

  if (ws_size >= need) {
    k_setup<<<dim3(5760), dim3(256), 0, stream>>>(x, kern, a, ws);
    k_route<<<dim3(1), dim3(512), 0, stream>>>(a, ws);
    k_convx<<<dim3(7, 4, 16), dim3(256), 0, stream>>>(bias, ws, out);
  } else {
    k_chanmax<<<dim3(IN_C), dim3(256), 0, stream>>>(x, ws);
    k_qhash<<<dim3(1), dim3(256), 0, stream>>>(a, ws);
    k_khash<<<dim3(OUT_C), dim3(256), 0, stream>>>(kern, a, ws);
    k_select<<<dim3(1), dim3(512), 0, stream>>>(ws);
    k_prep<<<dim3(OUT_C), dim3(256), 0, stream>>>(kern, ws);
    k_biasfill<<<dim3(4096), dim3(256), 0, stream>>>(bias, ws, out);
    k_conv<<<dim3(14, 4, 16), dim3(256), 0, stream>>>(x, bias, ws, out);
  }
}